// Round 5
// baseline (105.720 us; speedup 1.0000x reference)
//
#include <hip/hip_runtime.h>
#include <hip/hip_cooperative_groups.h>

namespace cg = cooperative_groups;

#define B_ 4
#define N_ 256
#define T_ 16
#define F_ 128
#define H_ 256
#define BN_ (B_ * N_)  // 1024

// ---------------------------------------------------------------------------
// Single cooperative kernel, 256 blocks x 1024 threads (all co-resident:
// 16 waves/CU, 64 KB LDS, 1 block/CU). grid.sync() between phases replaces
// two kernel launches (~5-7us each in the timed graph path).
//
// Phase 1: block bk computes hbar rows 4bk..4bk+3 (time-mean, coalesced) and
//          transposes W1 row bk into W1T[k][bk].
// Phase 2: block bk = (tile8 = bk>>1, h-half = bk&1). 1024 threads =
//          (kq in 0..7, hl in 0..127): dual GEMM over 16-wide k chunk,
//          W1T loads lane-coalesced, hbar uniform-address, 16 accs.
//          64 KB LDS reduction over kq. Outputs aT[tile4][h][4] (b1 folded),
//          cT[b][h][N].
// Phase 3: block = 4-row i-tile (R3's lp_k2 verbatim): 1024 threads =
//          (hq, j); logits = sum_h relu(a[h][i] + c[h][j]) * W2[h] + b2.
// ---------------------------------------------------------------------------
__global__ __launch_bounds__(1024) void lp_fused(const float* __restrict__ nf,
                                                 const float* __restrict__ W1,
                                                 const float* __restrict__ b1,
                                                 const float* __restrict__ W2,
                                                 const float* __restrict__ b2,
                                                 float* __restrict__ out,
                                                 float* __restrict__ hbar,
                                                 float* __restrict__ W1T,
                                                 float* __restrict__ aT,
                                                 float* __restrict__ cT) {
    __shared__ float smem[16384];  // 64 KB, re-used per phase

    cg::grid_group grid = cg::this_grid();
    const int bk  = blockIdx.x;   // 0..255
    const int tid = threadIdx.x;  // 0..1023

    // ================= phase 1: hbar + W1T =================
    if (tid < 512) {
        const int n  = tid >> 7;      // 0..3
        const int f  = tid & 127;
        const int bn = bk * 4 + n;
        const float* src = nf + (size_t)bn * (T_ * F_) + f;
        float s = 0.f;
#pragma unroll
        for (int t = 0; t < T_; ++t) s += src[t * F_];
        hbar[(size_t)bn * F_ + f] = s * (1.0f / 16.0f);
    } else if (tid < 768) {
        const int k = tid - 512;      // 0..255
        // coalesced read of W1 row bk; scattered write (fire-and-forget)
        W1T[(size_t)k * H_ + bk] = W1[(size_t)bk * 256 + k];
    }
    grid.sync();

    // ================= phase 2: dual GEMM =================
    {
        const int tile8 = bk >> 1;         // 0..127 -> 8 nodes
        const int h0    = (bk & 1) * 128;  // h half
        const int bn0   = tile8 * 8;
        const int b     = bn0 >> 8;
        const int kq    = tid >> 7;        // 0..7 (wave-uniform)
        const int hl    = tid & 127;
        const int h     = h0 + hl;

        const float* wA = W1T + (size_t)(kq * 16) * H_ + h;
        const float* wC = W1T + (size_t)(F_ + kq * 16) * H_ + h;
        const float* hb = hbar + (size_t)bn0 * F_ + kq * 16;  // uniform base

        float acca[8] = {0.f, 0.f, 0.f, 0.f, 0.f, 0.f, 0.f, 0.f};
        float accc[8] = {0.f, 0.f, 0.f, 0.f, 0.f, 0.f, 0.f, 0.f};

#pragma unroll
        for (int kk = 0; kk < 16; ++kk) {
            const float wa = wA[(size_t)kk * H_];   // coalesced over lanes (h)
            const float wc = wC[(size_t)kk * H_];
#pragma unroll
            for (int n = 0; n < 8; ++n) {
                const float hv = hb[n * F_ + kk];   // uniform address
                acca[n] = fmaf(hv, wa, acca[n]);
                accc[n] = fmaf(hv, wc, accc[n]);
            }
        }

        // red(v, kq, hl) = smem[(v*8+kq)*128 + hl]; lanes = hl -> conflict-free
#pragma unroll
        for (int n = 0; n < 8; ++n) {
            smem[((n)     * 8 + kq) * 128 + hl] = acca[n];
            smem[((8 + n) * 8 + kq) * 128 + hl] = accc[n];
        }
        __syncthreads();

        // 2048 outputs (16 vals x 128 hl); each thread finishes 2
#pragma unroll
        for (int i = 0; i < 2; ++i) {
            const int o   = tid + i * 1024;
            const int v   = o >> 7;       // 0..15
            const int hl2 = o & 127;
            const int h2  = h0 + hl2;
            float s = 0.f;
#pragma unroll
            for (int q = 0; q < 8; ++q) s += smem[(v * 8 + q) * 128 + hl2];
            if (v < 8) {
                const int bn = bn0 + v;
                aT[((size_t)(bn >> 2) * H_ + h2) * 4 + (bn & 3)] = s + b1[h2];
            } else {
                const int n = v - 8;
                cT[((size_t)b * H_ + h2) * N_ + ((bn0 & 255) + n)] = s;
            }
        }
    }
    grid.sync();

    // ================= phase 3: edge scores (R3 lp_k2) =================
    {
        const int tile = bk;           // 0..255
        const int bn0  = tile * 4;
        const int b    = bn0 >> 8;
        const int i0   = bn0 & 255;
        const int hq   = tid >> 8;     // 0..3 (wave-uniform)
        const int j    = tid & 255;

        const float* crow = cT + (size_t)b * (H_ * N_) + j;
        const float* arow = aT + (size_t)tile * (H_ * 4);  // [h][4], uniform
        const int h0 = hq * 64;

        float acc0 = 0.f, acc1 = 0.f, acc2 = 0.f, acc3 = 0.f;

#pragma unroll 8
        for (int hh = 0; hh < 64; ++hh) {
            const int h = h0 + hh;
            const float cj = crow[(size_t)h * N_];             // coalesced over j
            const float w  = W2[h];                            // uniform
            const float4 av = *(const float4*)(arow + h * 4);  // uniform
            float x;
            x = av.x + cj; acc0 = fmaf(fmaxf(x, 0.f), w, acc0);
            x = av.y + cj; acc1 = fmaf(fmaxf(x, 0.f), w, acc1);
            x = av.z + cj; acc2 = fmaf(fmaxf(x, 0.f), w, acc2);
            x = av.w + cj; acc3 = fmaf(fmaxf(x, 0.f), w, acc3);
        }

        // pr(row, hq, j) = smem[(row*4+hq)*256 + j]; lanes = j -> conflict-free
        smem[(0 * 4 + hq) * 256 + j] = acc0;
        smem[(1 * 4 + hq) * 256 + j] = acc1;
        smem[(2 * 4 + hq) * 256 + j] = acc2;
        smem[(3 * 4 + hq) * 256 + j] = acc3;
        __syncthreads();

        const int r  = tid >> 8;
        const int jj = tid & 255;
        const float s = (smem[(r * 4 + 0) * 256 + jj] + smem[(r * 4 + 1) * 256 + jj]) +
                        (smem[(r * 4 + 2) * 256 + jj] + smem[(r * 4 + 3) * 256 + jj]);
        out[((size_t)b * N_ + (i0 + r)) * N_ + jj] = s + b2[0];
    }
}

extern "C" void kernel_launch(void* const* d_in, const int* in_sizes, int n_in,
                              void* d_out, int out_size, void* d_ws, size_t ws_size,
                              hipStream_t stream) {
    const float* nodefeat = (const float*)d_in[0];  // [B,N,T,F]
    const float* W1       = (const float*)d_in[1];  // [H, 2F]
    const float* b1       = (const float*)d_in[2];  // [H]
    const float* W2       = (const float*)d_in[3];  // [1, H]
    const float* b2       = (const float*)d_in[4];  // [1]
    float* out = (float*)d_out;                     // [B,N,N]

    float* hbar = (float*)d_ws;                     // [1024][128]       = 512 KB
    float* W1T  = hbar + (size_t)BN_ * F_;          // [256][256]        = 256 KB
    float* aT   = W1T + 256 * 256;                  // [256 tiles][H][4] = 1 MB
    float* cT   = aT + (size_t)256 * H_ * 4;        // [B][H][N]         = 1 MB

    void* args[] = {(void*)&nodefeat, (void*)&W1, (void*)&b1, (void*)&W2,
                    (void*)&b2, (void*)&out, (void*)&hbar, (void*)&W1T,
                    (void*)&aT, (void*)&cT};
    hipLaunchCooperativeKernel((const void*)lp_fused, dim3(256), dim3(1024),
                               args, 0, stream);
}

// Round 6
// 45.649 us; speedup vs baseline: 2.3159x; 2.3159x over previous
//
#include <hip/hip_runtime.h>

#define B_ 4
#define N_ 256
#define T_ 16
#define F_ 128
#define H_ 256
#define BN_ (B_ * N_)  // 1024

// ---------------------------------------------------------------------------
// DIAGNOSTIC ROUND: identical kernels to round 3, but lp_k2 is launched 4x
// (idempotent: reads aT/cT, overwrites out with the same values each time).
// dur = F + prep + gemm + 4*k2;  round-3 dur = F + prep + gemm + k2 = 25.7us
// => k2 = (dur - 25.7)/3. Distinguishes harness-overhead (A) vs kernel-bound
// (B) hypotheses.
// ---------------------------------------------------------------------------

// lp_prep: blocks 0..127  : hbar[bn][f] = mean_t nodefeat[bn][t][f]
//          blocks 128..143: W1T[k][h] = W1[h][k]   (LDS-tiled transpose)
__global__ __launch_bounds__(1024) void lp_prep(const float* __restrict__ nf,
                                                const float* __restrict__ W1,
                                                float* __restrict__ hbar,
                                                float* __restrict__ W1T) {
    __shared__ float sT[64][65];
    const int tid = threadIdx.x;
    if (blockIdx.x < 128) {
        const int idx = blockIdx.x * 1024 + tid;   // bn*128 + f
        const int bn  = idx >> 7;
        const int f   = idx & 127;
        const float* src = nf + (size_t)bn * (T_ * F_) + f;
        float s = 0.f;
#pragma unroll
        for (int t = 0; t < T_; ++t) s += src[t * F_];
        hbar[idx] = s * (1.0f / 16.0f);
    } else {
        const int t  = blockIdx.x - 128;  // 0..15
        const int y0 = (t >> 2) * 64;     // h-tile base
        const int x0 = (t & 3) * 64;      // k-tile base
        const int ty = tid >> 6;          // 0..15
        const int tx = tid & 63;
#pragma unroll
        for (int r = 0; r < 4; ++r)
            sT[r * 16 + ty][tx] = W1[(size_t)(y0 + r * 16 + ty) * 256 + (x0 + tx)];
        __syncthreads();
#pragma unroll
        for (int r = 0; r < 4; ++r)
            W1T[(size_t)(x0 + r * 16 + ty) * 256 + (y0 + tx)] = sT[tx][r * 16 + ty];
    }
}

// lp_gemm: block = (8-node tile, h-half), 512 threads = (kq 0..3, hl 0..127).
// W1T loads lane-coalesced; hbar via wave-uniform s_load.
// Outputs: aT[tile4][h][4] (b1 folded), cT[b][h][N].
__global__ __launch_bounds__(512) void lp_gemm(const float* __restrict__ hbar,
                                               const float* __restrict__ W1T,
                                               const float* __restrict__ b1,
                                               float* __restrict__ aT,
                                               float* __restrict__ cT) {
    __shared__ float red[16][4][128];  // [val][kq][hl] = 32 KB

    const int tile8 = blockIdx.x >> 1;        // 0..127 -> 8 nodes
    const int h0    = (blockIdx.x & 1) * 128; // h half
    const int bn0   = tile8 * 8;
    const int b     = bn0 >> 8;
    const int tid   = threadIdx.x;
    const int kq    = __builtin_amdgcn_readfirstlane(tid >> 7);  // 0..3
    const int hl    = tid & 127;
    const int h     = h0 + hl;

    const float* wA = W1T + (size_t)(kq * 32) * H_ + h;
    const float* wC = W1T + (size_t)(F_ + kq * 32) * H_ + h;
    const float* hb = hbar + (size_t)bn0 * F_ + kq * 32;  // wave-uniform base

    float acca[8] = {0.f, 0.f, 0.f, 0.f, 0.f, 0.f, 0.f, 0.f};
    float accc[8] = {0.f, 0.f, 0.f, 0.f, 0.f, 0.f, 0.f, 0.f};

#pragma unroll 4
    for (int kk = 0; kk < 32; ++kk) {
        const float wa = wA[(size_t)kk * H_];   // coalesced over lanes
        const float wc = wC[(size_t)kk * H_];
#pragma unroll
        for (int n = 0; n < 8; ++n) {
            const float hv = hb[n * F_ + kk];   // uniform -> s_load
            acca[n] = fmaf(hv, wa, acca[n]);
            accc[n] = fmaf(hv, wc, accc[n]);
        }
    }

#pragma unroll
    for (int n = 0; n < 8; ++n) {
        red[n][kq][hl]     = acca[n];
        red[8 + n][kq][hl] = accc[n];
    }
    __syncthreads();

    const int rv = tid >> 7;  // 0..3
#pragma unroll
    for (int i = 0; i < 4; ++i) {
        const int v = rv * 4 + i;  // 0..15
        const float s = (red[v][0][hl] + red[v][1][hl]) + (red[v][2][hl] + red[v][3][hl]);
        if (v < 8) {
            const int bn = bn0 + v;
            aT[((size_t)(bn >> 2) * H_ + h) * 4 + (bn & 3)] = s + b1[h];
        } else {
            const int n = v - 8;
            cT[((size_t)b * H_ + h) * N_ + ((bn0 & 255) + n)] = s;
        }
    }
}

// lp_k2: block = (b, 4-row i-tile), 1024 threads = (hq 0..3, j 0..255).
// (round-3 version verbatim)
__global__ __launch_bounds__(1024) void lp_k2(const float* __restrict__ aT,
                                              const float* __restrict__ cT,
                                              const float* __restrict__ W2,
                                              const float* __restrict__ b2,
                                              float* __restrict__ out) {
    __shared__ float pr[4][4][256];  // [row][hq][j] = 16 KB

    const int tile = blockIdx.x;  // 0..255
    const int bn0  = tile * 4;
    const int b    = bn0 >> 8;
    const int i0   = bn0 & 255;
    const int tid  = threadIdx.x;
    const int hq   = __builtin_amdgcn_readfirstlane(tid >> 8);  // 0..3
    const int j    = tid & 255;

    const float* crow = cT + (size_t)b * (H_ * N_) + j;
    const float* arow = aT + (size_t)tile * (H_ * 4);  // [h][4], uniform base
    const int h0 = hq * 64;

    float acc0 = 0.f, acc1 = 0.f, acc2 = 0.f, acc3 = 0.f;

#pragma unroll 8
    for (int hh = 0; hh < 64; ++hh) {
        const int h = h0 + hh;
        const float cj = crow[(size_t)h * N_];             // coalesced over j
        const float w  = W2[h];                            // uniform -> s_load
        const float4 av = *(const float4*)(arow + h * 4);  // uniform -> s_load
        float x;
        x = av.x + cj; acc0 = fmaf(fmaxf(x, 0.f), w, acc0);
        x = av.y + cj; acc1 = fmaf(fmaxf(x, 0.f), w, acc1);
        x = av.z + cj; acc2 = fmaf(fmaxf(x, 0.f), w, acc2);
        x = av.w + cj; acc3 = fmaf(fmaxf(x, 0.f), w, acc3);
    }

    pr[0][hq][j] = acc0;
    pr[1][hq][j] = acc1;
    pr[2][hq][j] = acc2;
    pr[3][hq][j] = acc3;
    __syncthreads();

    const int r  = tid >> 8;
    const int jj = tid & 255;
    const float s = (pr[r][0][jj] + pr[r][1][jj]) + (pr[r][2][jj] + pr[r][3][jj]);
    out[((size_t)b * N_ + (i0 + r)) * N_ + jj] = s + b2[0];
}

extern "C" void kernel_launch(void* const* d_in, const int* in_sizes, int n_in,
                              void* d_out, int out_size, void* d_ws, size_t ws_size,
                              hipStream_t stream) {
    const float* nodefeat = (const float*)d_in[0];  // [B,N,T,F]
    const float* W1       = (const float*)d_in[1];  // [H, 2F]
    const float* b1       = (const float*)d_in[2];  // [H]
    const float* W2       = (const float*)d_in[3];  // [1, H]
    const float* b2       = (const float*)d_in[4];  // [1]
    float* out = (float*)d_out;                     // [B,N,N]

    float* hbar = (float*)d_ws;                     // [1024][128]       = 512 KB
    float* W1T  = hbar + (size_t)BN_ * F_;          // [256][256]        = 256 KB
    float* aT   = W1T + 256 * 256;                  // [256 tiles][H][4] = 1 MB
    float* cT   = aT + (size_t)256 * H_ * 4;        // [B][H][N]         = 1 MB

    lp_prep<<<144, 1024, 0, stream>>>(nodefeat, W1, hbar, W1T);
    lp_gemm<<<256, 512, 0, stream>>>(hbar, W1T, b1, aT, cT);
    // k2 x4: idempotent replays isolate k2's duration:
    //   k2 = (dur_this_round - 25.7us) / 3
    lp_k2<<<256, 1024, 0, stream>>>(aT, cT, W2, b2, out);
    lp_k2<<<256, 1024, 0, stream>>>(aT, cT, W2, b2, out);
    lp_k2<<<256, 1024, 0, stream>>>(aT, cT, W2, b2, out);
    lp_k2<<<256, 1024, 0, stream>>>(aT, cT, W2, b2, out);
}

// Round 7
// 25.446 us; speedup vs baseline: 4.1547x; 1.7940x over previous
//
#include <hip/hip_runtime.h>

#define B_ 4
#define N_ 256
#define T_ 16
#define F_ 128
#define H_ 256
#define BN_ (B_ * N_)  // 1024

// ---------------------------------------------------------------------------
// lp_prep: blocks 0..127  : hbar[bn][f] = mean_t nodefeat[bn][t][f]
//          blocks 128..143: W1T[k][h] = W1[h][k]   (LDS-tiled transpose)
// (unchanged from round 3)
// ---------------------------------------------------------------------------
__global__ __launch_bounds__(1024) void lp_prep(const float* __restrict__ nf,
                                                const float* __restrict__ W1,
                                                float* __restrict__ hbar,
                                                float* __restrict__ W1T) {
    __shared__ float sT[64][65];
    const int tid = threadIdx.x;
    if (blockIdx.x < 128) {
        const int idx = blockIdx.x * 1024 + tid;   // bn*128 + f
        const int bn  = idx >> 7;
        const int f   = idx & 127;
        const float* src = nf + (size_t)bn * (T_ * F_) + f;
        float s = 0.f;
#pragma unroll
        for (int t = 0; t < T_; ++t) s += src[t * F_];
        hbar[idx] = s * (1.0f / 16.0f);
    } else {
        const int t  = blockIdx.x - 128;  // 0..15
        const int y0 = (t >> 2) * 64;     // h-tile base
        const int x0 = (t & 3) * 64;      // k-tile base
        const int ty = tid >> 6;          // 0..15
        const int tx = tid & 63;
#pragma unroll
        for (int r = 0; r < 4; ++r)
            sT[r * 16 + ty][tx] = W1[(size_t)(y0 + r * 16 + ty) * 256 + (x0 + tx)];
        __syncthreads();
#pragma unroll
        for (int r = 0; r < 4; ++r)
            W1T[(size_t)(x0 + r * 16 + ty) * 256 + (y0 + tx)] = sT[tx][r * 16 + ty];
    }
}

// ---------------------------------------------------------------------------
// lp_gemm: block = (8-node tile, h-half), 512 threads = (kq 0..3, hl 0..127).
// W1T loads lane-coalesced; hbar via wave-uniform s_load.
// Outputs: aT[tile4][h][4] (b1 folded), cT[b][h][N].
// (unchanged from round 3)
// ---------------------------------------------------------------------------
__global__ __launch_bounds__(512) void lp_gemm(const float* __restrict__ hbar,
                                               const float* __restrict__ W1T,
                                               const float* __restrict__ b1,
                                               float* __restrict__ aT,
                                               float* __restrict__ cT) {
    __shared__ float red[16][4][128];  // [val][kq][hl] = 32 KB

    const int tile8 = blockIdx.x >> 1;        // 0..127 -> 8 nodes
    const int h0    = (blockIdx.x & 1) * 128; // h half
    const int bn0   = tile8 * 8;
    const int b     = bn0 >> 8;
    const int tid   = threadIdx.x;
    const int kq    = __builtin_amdgcn_readfirstlane(tid >> 7);  // 0..3
    const int hl    = tid & 127;
    const int h     = h0 + hl;

    const float* wA = W1T + (size_t)(kq * 32) * H_ + h;
    const float* wC = W1T + (size_t)(F_ + kq * 32) * H_ + h;
    const float* hb = hbar + (size_t)bn0 * F_ + kq * 32;  // wave-uniform base

    float acca[8] = {0.f, 0.f, 0.f, 0.f, 0.f, 0.f, 0.f, 0.f};
    float accc[8] = {0.f, 0.f, 0.f, 0.f, 0.f, 0.f, 0.f, 0.f};

#pragma unroll 4
    for (int kk = 0; kk < 32; ++kk) {
        const float wa = wA[(size_t)kk * H_];   // coalesced over lanes
        const float wc = wC[(size_t)kk * H_];
#pragma unroll
        for (int n = 0; n < 8; ++n) {
            const float hv = hb[n * F_ + kk];   // uniform -> s_load
            acca[n] = fmaf(hv, wa, acca[n]);
            accc[n] = fmaf(hv, wc, accc[n]);
        }
    }

#pragma unroll
    for (int n = 0; n < 8; ++n) {
        red[n][kq][hl]     = acca[n];
        red[8 + n][kq][hl] = accc[n];
    }
    __syncthreads();

    const int rv = tid >> 7;  // 0..3
#pragma unroll
    for (int i = 0; i < 4; ++i) {
        const int v = rv * 4 + i;  // 0..15
        const float s = (red[v][0][hl] + red[v][1][hl]) + (red[v][2][hl] + red[v][3][hl]);
        if (v < 8) {
            const int bn = bn0 + v;
            aT[((size_t)(bn >> 2) * H_ + h) * 4 + (bn & 3)] = s + b1[h];
        } else {
            const int n = v - 8;
            cT[((size_t)b * H_ + h) * N_ + ((bn0 & 255) + n)] = s;
        }
    }
}

// ---------------------------------------------------------------------------
// lp_k2 v3: block = 8 rows x 128 j  (grid 256 = 4 b x 32 i-tiles x 2 j-halves)
// 1024 threads = (ho in 0..7 = 32-wide h-chunk, jl in 0..127).
// Per h-iter: 1 coalesced cT dword + 2 uniform s_load_dwordx4 (a-pairs) +
// 24 VALU. Per-block cT traffic = 128h x 128j... full h x 128 j = 128 KB ->
// 32 MB total L2 traffic (half of v1's 64 MB). LDS 32 KB ho-reduction.
// ---------------------------------------------------------------------------
__global__ __launch_bounds__(1024) void lp_k2(const float* __restrict__ aT,
                                              const float* __restrict__ cT,
                                              const float* __restrict__ W2,
                                              const float* __restrict__ b2,
                                              float* __restrict__ out) {
    __shared__ float pr[8][8][128];  // [ho][i][jl] = 32 KB

    const int bx  = blockIdx.x;      // 0..255
    const int b   = bx >> 6;         // 0..3
    const int rr  = bx & 63;
    const int it  = rr >> 1;         // 0..31 : i-tile of 8 rows
    const int jh  = rr & 1;          // j half
    const int i0  = it * 8;
    const int j0  = jh * 128;
    const int bn0 = b * N_ + i0;

    const int tid = threadIdx.x;
    const int ho  = __builtin_amdgcn_readfirstlane(tid >> 7);  // 0..7, wave-uniform
    const int jl  = tid & 127;

    const float* crow = cT + (size_t)b * (H_ * N_) + j0 + jl;
    // aT[tile4][h][4]: rows i0..i0+7 span tile4 = bn0>>2 and bn0>>2 + 1
    const float* a0 = aT + (size_t)(bn0 >> 2) * (H_ * 4);       // uniform base
    const float* a1 = a0 + H_ * 4;
    const int h0 = ho * 32;

    float acc0 = 0.f, acc1 = 0.f, acc2 = 0.f, acc3 = 0.f;
    float acc4 = 0.f, acc5 = 0.f, acc6 = 0.f, acc7 = 0.f;

#pragma unroll 4
    for (int hh = 0; hh < 32; ++hh) {
        const int h = h0 + hh;
        const float  cj  = crow[(size_t)h * N_];           // coalesced over jl
        const float  w   = W2[h];                          // uniform -> s_load
        const float4 av0 = *(const float4*)(a0 + h * 4);   // uniform -> s_load_dwordx4
        const float4 av1 = *(const float4*)(a1 + h * 4);   // uniform -> s_load_dwordx4
        float x;
        x = av0.x + cj; acc0 = fmaf(fmaxf(x, 0.f), w, acc0);
        x = av0.y + cj; acc1 = fmaf(fmaxf(x, 0.f), w, acc1);
        x = av0.z + cj; acc2 = fmaf(fmaxf(x, 0.f), w, acc2);
        x = av0.w + cj; acc3 = fmaf(fmaxf(x, 0.f), w, acc3);
        x = av1.x + cj; acc4 = fmaf(fmaxf(x, 0.f), w, acc4);
        x = av1.y + cj; acc5 = fmaf(fmaxf(x, 0.f), w, acc5);
        x = av1.z + cj; acc6 = fmaf(fmaxf(x, 0.f), w, acc6);
        x = av1.w + cj; acc7 = fmaf(fmaxf(x, 0.f), w, acc7);
    }

    pr[ho][0][jl] = acc0;
    pr[ho][1][jl] = acc1;
    pr[ho][2][jl] = acc2;
    pr[ho][3][jl] = acc3;
    pr[ho][4][jl] = acc4;
    pr[ho][5][jl] = acc5;
    pr[ho][6][jl] = acc6;
    pr[ho][7][jl] = acc7;
    __syncthreads();

    // combine: 1024 threads -> 8 i x 128 j outputs
    const int oi = tid >> 7;   // 0..7
    const int oj = tid & 127;
    float s = 0.f;
#pragma unroll
    for (int o = 0; o < 8; ++o) s += pr[o][oi][oj];
    out[(size_t)(bn0 + oi) * N_ + j0 + oj] = s + b2[0];
}

extern "C" void kernel_launch(void* const* d_in, const int* in_sizes, int n_in,
                              void* d_out, int out_size, void* d_ws, size_t ws_size,
                              hipStream_t stream) {
    const float* nodefeat = (const float*)d_in[0];  // [B,N,T,F]
    const float* W1       = (const float*)d_in[1];  // [H, 2F]
    const float* b1       = (const float*)d_in[2];  // [H]
    const float* W2       = (const float*)d_in[3];  // [1, H]
    const float* b2       = (const float*)d_in[4];  // [1]
    float* out = (float*)d_out;                     // [B,N,N]

    float* hbar = (float*)d_ws;                     // [1024][128]       = 512 KB
    float* W1T  = hbar + (size_t)BN_ * F_;          // [256][256]        = 256 KB
    float* aT   = W1T + 256 * 256;                  // [256 tiles][H][4] = 1 MB
    float* cT   = aT + (size_t)256 * H_ * 4;        // [B][H][N]         = 1 MB

    lp_prep<<<144, 1024, 0, stream>>>(nodefeat, W1, hbar, W1T);
    lp_gemm<<<256, 512, 0, stream>>>(hbar, W1T, b1, aT, cT);
    lp_k2<<<256, 1024, 0, stream>>>(aT, cT, W2, b2, out);
}